// Round 3
// baseline (44.665 us; speedup 1.0000x reference)
//
#include <hip/hip_runtime.h>
#include <math.h>

#define S 256
#define H 1024
#define NTAG 20
#define NPAIR 32640  // S*(S-1)/2

// ---- workspace layout (float indices) ----
#define WS_T     0          // [8 kc][256 s][1024 c] score GEMM partials (8 MB)
#define WS_HP    2097152    // [8 kc][3 p][256 s][20 t] hw partials (480 KB)
#define WS_A     2220032    // [256] raw scores (pre-b2)
#define WS_ZC    2220544    // [257]
#define WS_HW0   2220804    // [256*20] (16B-aligned)
#define WS_HW1   2225924    // [256*20]
#define WS_HW2   2231044    // [256*20]
#define WS_PW    2236164    // [257*20]
#define WS_LW    2241304    // [257*20] indexed by L=j-i+1 in [2,256]
#define WS_LOSSP 2246444    // [128]
#define WS_RUN   2246572    // int[256]
#define WS_START 2246828    // int[256]
#define WS_END   2247084    // int[256]

// Kernel G: all K-split GEMM partials in one launch.
//   b<512:       score partials: cg=b&3, rg=(b>>2)&15, kc=b>>6
//   512<=b<640:  hw partials:    rg=hb&15, kc=hb>>4
__global__ __launch_bounds__(256) void kG(const float* __restrict__ hidden,
                                          const float* __restrict__ w1,
                                          const float* __restrict__ fcw,
                                          float* __restrict__ ws) {
    const int tid = threadIdx.x;
    const int b = blockIdx.x;
    __shared__ __align__(16) float shbuf[128 * 20];  // 10 KB, shared by both paths

    if (b < 512) {
        const int cg = b & 3, rg = (b >> 2) & 15, kc = b >> 6;
        float (*shH)[20] = (float(*)[20])shbuf;   // [k][row], stride 20: 8-way wr conflict, fp4-aligned reads
        const int kk = tid & 127;
        const int r0 = (tid >> 7) * 8;
        #pragma unroll
        for (int e = 0; e < 8; e++)
            shH[kk][r0 + e] = hidden[(rg * 16 + r0 + e) * H + kc * 128 + kk];
        __syncthreads();

        float acc[16];
        #pragma unroll
        for (int r = 0; r < 16; r++) acc[r] = 0.f;

        const float* wp = w1 + (size_t)(kc * 128) * H + cg * 256 + tid;
        #pragma unroll 4
        for (int k = 0; k < 128; k++) {
            const float wv = wp[k * H];
            const float4 h0 = *(const float4*)&shH[k][0];   // wave-uniform -> broadcast
            const float4 h1 = *(const float4*)&shH[k][4];
            const float4 h2 = *(const float4*)&shH[k][8];
            const float4 h3 = *(const float4*)&shH[k][12];
            acc[0]  = fmaf(h0.x, wv, acc[0]);  acc[1]  = fmaf(h0.y, wv, acc[1]);
            acc[2]  = fmaf(h0.z, wv, acc[2]);  acc[3]  = fmaf(h0.w, wv, acc[3]);
            acc[4]  = fmaf(h1.x, wv, acc[4]);  acc[5]  = fmaf(h1.y, wv, acc[5]);
            acc[6]  = fmaf(h1.z, wv, acc[6]);  acc[7]  = fmaf(h1.w, wv, acc[7]);
            acc[8]  = fmaf(h2.x, wv, acc[8]);  acc[9]  = fmaf(h2.y, wv, acc[9]);
            acc[10] = fmaf(h2.z, wv, acc[10]); acc[11] = fmaf(h2.w, wv, acc[11]);
            acc[12] = fmaf(h3.x, wv, acc[12]); acc[13] = fmaf(h3.y, wv, acc[13]);
            acc[14] = fmaf(h3.z, wv, acc[14]); acc[15] = fmaf(h3.w, wv, acc[15]);
        }
        float* op = ws + WS_T + kc * (S * H) + (rg * 16) * H + cg * 256 + tid;
        #pragma unroll
        for (int r = 0; r < 16; r++) op[r * H] = acc[r];
    } else {
        const int hb = b - 512;
        const int rg = hb & 15, kc = hb >> 4;
        float (*shHT)[17] = (float(*)[17])shbuf;  // [k][row], stride 17: conflict-free both sides
        {
            const int c = tid & 127, rr = tid >> 7;
            #pragma unroll
            for (int e = 0; e < 8; e++) {
                const int r = e * 2 + rr;
                shHT[c][r] = hidden[(rg * 16 + r) * H + kc * 128 + c];
            }
        }
        __syncthreads();
        if (tid < 240) {
            const int t = tid % 20, g = tid / 20;   // g 0..11
            const int p = g >> 2, rsub = g & 3;     // p 0..2, rows rsub*4..+3
            const float* fw = fcw + (size_t)(p * H + kc * 128) * 20 + t;
            float a0 = 0.f, a1 = 0.f, a2 = 0.f, a3 = 0.f;
            #pragma unroll 8
            for (int k = 0; k < 128; k++) {
                const float w = fw[k * 20];          // 80B/wave, near-broadcast
                a0 = fmaf(shHT[k][rsub * 4 + 0], w, a0);
                a1 = fmaf(shHT[k][rsub * 4 + 1], w, a1);
                a2 = fmaf(shHT[k][rsub * 4 + 2], w, a2);
                a3 = fmaf(shHT[k][rsub * 4 + 3], w, a3);
            }
            float* hp = ws + WS_HP + ((size_t)(kc * 3 + p) * 256 + rg * 16 + rsub * 4) * 20 + t;
            hp[0]  = a0; hp[20] = a1; hp[40] = a2; hp[60] = a3;
        }
    }
}

// Kernel R: per-row (block b = row s): score slab reduce -> tanh -> dot(w2);
// plus 8-way hw partial reduce -> hw0/hw1/hw2 tables.
__global__ __launch_bounds__(256) void kR(const float* __restrict__ b1,
                                          const float* __restrict__ w2,
                                          float* __restrict__ ws) {
    const int b = blockIdx.x, tid = threadIdx.x;
    __shared__ float sred[256];
    float lacc = 0.f;
    #pragma unroll
    for (int q = 0; q < 4; q++) {
        const int c = q * 256 + tid;
        float sum = 0.f;
        #pragma unroll
        for (int kcz = 0; kcz < 8; kcz++)
            sum += ws[WS_T + kcz * (S * H) + b * H + c];
        lacc += tanhf(sum + b1[c]) * w2[c];
    }
    sred[tid] = lacc;
    __syncthreads();
    for (int off = 128; off > 0; off >>= 1) {
        if (tid < off) sred[tid] += sred[tid + off];
        __syncthreads();
    }
    if (tid == 0) ws[WS_A + b] = sred[0];

    if (tid < 60) {
        const int t = tid % 20, p = tid / 20;
        float s = 0.f;
        #pragma unroll
        for (int kc = 0; kc < 8; kc++)
            s += ws[WS_HP + ((size_t)(kc * 3 + p) * 256 + b) * 20 + t];
        const int base = (p == 0) ? WS_HW0 : (p == 1) ? WS_HW1 : WS_HW2;
        ws[base + b * 20 + t] = s;
    }
}

// Kernel S: 1 block: lw table, max, e, Zc/run scans, start/end, Pw cumsum.
__global__ __launch_bounds__(256) void kS(const float* __restrict__ b2,
                                          const int* __restrict__ target,
                                          const float* __restrict__ lenemb,
                                          const float* __restrict__ fcw,
                                          float* __restrict__ ws) {
    const int s = threadIdx.x;
    __shared__ float shf[256], she[256];
    __shared__ int shi[256], shtg[256];
    __shared__ float shw0[5120];

    for (int item = s; item < 255 * 20; item += 256) {
        const int L = 2 + item / 20, t = item % 20;
        float v = 0.f;
        #pragma unroll
        for (int d = 0; d < 10; d++)
            v = fmaf(lenemb[L * 10 + d], fcw[(3072 + d) * 20 + t], v);
        ws[WS_LW + L * 20 + t] = v;
    }

    shtg[s] = target[s];
    const float a = ws[WS_A + s] + b2[0];
    shf[s] = a;
    __syncthreads();
    for (int off = 128; off > 0; off >>= 1) {
        if (s < off) shf[s] = fmaxf(shf[s], shf[s + off]);
        __syncthreads();
    }
    const float mx = shf[0];
    __syncthreads();
    const float ev = expf(a - mx);
    she[s] = ev;
    shf[s] = ev;
    const int chg = (s == 0) ? 1 : (shtg[s] != shtg[s - 1]);
    shi[s] = chg;
    __syncthreads();
    for (int off = 1; off < 256; off <<= 1) {
        const float fv = (s >= off) ? shf[s - off] : 0.f;
        const int   iv = (s >= off) ? shi[s - off] : 0;
        __syncthreads();
        shf[s] += fv;
        shi[s] += iv;
        __syncthreads();
    }
    ws[WS_ZC + s + 1] = shf[s];
    if (s == 0) ws[WS_ZC] = 0.f;
    ((int*)ws)[WS_RUN + s]   = shi[s];
    ((int*)ws)[WS_START + s] = chg;
    ((int*)ws)[WS_END + s]   = (s == 255) ? 1 : (shtg[s] != shtg[s + 1]);

    for (int idx = s; idx < 5120; idx += 256) shw0[idx] = ws[WS_HW0 + idx];
    __syncthreads();
    if (s < 20) {
        float pw = 0.f;
        ws[WS_PW + s] = 0.f;
        for (int s2 = 0; s2 < 256; s2++) {
            pw = fmaf(she[s2], shw0[s2 * 20 + s], pw);
            ws[WS_PW + (s2 + 1) * 20 + s] = pw;
        }
    }
}

// Kernel E: flattened pairs. thread -> pair p; recover (i,j) from triangular index.
__global__ __launch_bounds__(256) void kE(const int* __restrict__ target,
                                          const float* __restrict__ fcb,
                                          float* __restrict__ out,
                                          float* __restrict__ ws) {
    const int tid = threadIdx.x;
    const int p = blockIdx.x * 256 + tid;
    __shared__ float sred[256];
    float lossacc = 0.f;
    if (p < NPAIR) {
        // p = i*255 - i(i-1)/2 + (j-i-1);  f(i) = i*(511-i)/2. All exact in fp32.
        int i = (int)((511.0f - sqrtf((float)(261121 - 8 * p))) * 0.5f);
        while ((i + 1) * (510 - i) <= 2 * p) ++i;
        while (i > 0 && i * (511 - i) > 2 * p) --i;
        const int j = p - i * (511 - i) / 2 + i + 1;

        const float Zci  = ws[WS_ZC + i];
        const float invz = 1.f / (ws[WS_ZC + j + 1] - Zci);
        const int L = j - i + 1;
        const int* runid = (const int*)ws + WS_RUN;
        const int* stA   = (const int*)ws + WS_START;
        const int* enA   = (const int*)ws + WS_END;
        const int lbl = (runid[i] == runid[j] && stA[i] && enA[j]) ? target[j] : 0;

        const float4* pwj4 = (const float4*)(ws + WS_PW + (j + 1) * 20);
        const float4* pwi4 = (const float4*)(ws + WS_PW + i * 20);
        const float4* h14  = (const float4*)(ws + WS_HW1 + i * 20);
        const float4* h24  = (const float4*)(ws + WS_HW2 + j * 20);
        const float4* lw4  = (const float4*)(ws + WS_LW + L * 20);
        const float4* fb4  = (const float4*)fcb;
        float4* op4 = (float4*)(out + (size_t)p * 20);

        float lg[20];
        float mx = -1e30f, chosen = 0.f;
        #pragma unroll
        for (int q = 0; q < 5; q++) {
            const float4 aj = pwj4[q], ai = pwi4[q];
            const float4 bi = h14[q],  bj = h24[q];
            const float4 cl = lw4[q],  fb = fb4[q];
            float4 r;
            r.x = (aj.x - ai.x) * invz + bi.x + bj.x + cl.x + fb.x;
            r.y = (aj.y - ai.y) * invz + bi.y + bj.y + cl.y + fb.y;
            r.z = (aj.z - ai.z) * invz + bi.z + bj.z + cl.z + fb.z;
            r.w = (aj.w - ai.w) * invz + bi.w + bj.w + cl.w + fb.w;
            op4[q] = r;
            lg[q * 4 + 0] = r.x; lg[q * 4 + 1] = r.y;
            lg[q * 4 + 2] = r.z; lg[q * 4 + 3] = r.w;
            mx = fmaxf(mx, fmaxf(fmaxf(r.x, r.y), fmaxf(r.z, r.w)));
            chosen = (q * 4 + 0 == lbl) ? r.x : chosen;
            chosen = (q * 4 + 1 == lbl) ? r.y : chosen;
            chosen = (q * 4 + 2 == lbl) ? r.z : chosen;
            chosen = (q * 4 + 3 == lbl) ? r.w : chosen;
        }
        float se = 0.f;
        #pragma unroll
        for (int t = 0; t < 20; t++) se += expf(lg[t] - mx);
        lossacc = -(chosen - mx - logf(se));
    }
    sred[tid] = lossacc;
    __syncthreads();
    for (int off = 128; off > 0; off >>= 1) {
        if (tid < off) sred[tid] += sred[tid + off];
        __syncthreads();
    }
    if (tid == 0) ws[WS_LOSSP + blockIdx.x] = sred[0];
}

// Kernel F: final loss reduction over 128 block partials.
__global__ __launch_bounds__(128) void kF(float* __restrict__ out,
                                          float* __restrict__ ws) {
    __shared__ float sh[128];
    const int t = threadIdx.x;
    sh[t] = ws[WS_LOSSP + t];
    __syncthreads();
    for (int off = 64; off > 0; off >>= 1) {
        if (t < off) sh[t] += sh[t + off];
        __syncthreads();
    }
    if (t == 0) out[(size_t)NPAIR * 20] = sh[0] / (float)NPAIR;
}

extern "C" void kernel_launch(void* const* d_in, const int* in_sizes, int n_in,
                              void* d_out, int out_size, void* d_ws, size_t ws_size,
                              hipStream_t stream) {
    (void)in_sizes; (void)n_in; (void)out_size; (void)ws_size;
    const float* hidden = (const float*)d_in[0];
    const int*   target = (const int*)d_in[1];
    const float* w1     = (const float*)d_in[2];
    const float* b1     = (const float*)d_in[3];
    const float* w2     = (const float*)d_in[4];
    const float* b2     = (const float*)d_in[5];
    const float* lenemb = (const float*)d_in[6];
    const float* fcw    = (const float*)d_in[7];
    const float* fcb    = (const float*)d_in[8];
    float* out = (float*)d_out;
    float* ws  = (float*)d_ws;

    kG<<<640, 256, 0, stream>>>(hidden, w1, fcw, ws);
    kR<<<256, 256, 0, stream>>>(b1, w2, ws);
    kS<<<1, 256, 0, stream>>>(b2, target, lenemb, fcw, ws);
    kE<<<128, 256, 0, stream>>>(target, fcb, out, ws);
    kF<<<1, 128, 0, stream>>>(out, ws);
}